// Round 3
// baseline (3468.021 us; speedup 1.0000x reference)
//
#include <hip/hip_runtime.h>

#define D_DIM 256
#define K_CODES 1024
#define S_STAGES 4
#define BETA 0.25f
#define DECAY 0.99f
#define EPS_F 1e-5f
#define NSPLIT 8

// ---------- sum of squares per code row, replicating numpy pairwise ----------
__global__ void k_sumsq(const float* __restrict__ cb, float* __restrict__ out) {
    #pragma clang fp contract(off)
    int i = blockIdx.x * blockDim.x + threadIdx.x;
    if (i >= S_STAGES * K_CODES) return;
    const float* p = cb + (size_t)i * D_DIM;
    float tot = 0.0f;
    for (int h = 0; h < 256; h += 128) {
        const float* q = p + h;
        float r[8];
        #pragma unroll
        for (int j = 0; j < 8; ++j) { float v = q[j]; r[j] = v * v; }
        for (int t = 8; t < 128; t += 8) {
            #pragma unroll
            for (int j = 0; j < 8; ++j) { float v = q[t + j]; r[j] = r[j] + v * v; }
        }
        float res = ((r[0] + r[1]) + (r[2] + r[3])) + ((r[4] + r[5]) + (r[6] + r[7]));
        tot = tot + res;
    }
    out[i] = tot;
}

// ---------- argmin over K for 128 tokens per block; residual recomputed ----------
// LDS: [row][64] floats, float4-granule swizzled: granule' = granule ^ ((row>>3)&7)
template<int SC>
__global__ __launch_bounds__(256, 2)
void k_argmin(const float* __restrict__ z,
              const float* __restrict__ cb,        // all stages [S*K*D]
              const int* __restrict__ idx_ws,      // [S][Nt] (read p<SC)
              const float* __restrict__ sumsq_s,   // + SC*K
              int* __restrict__ idx_int,           // + SC*Nt
              float* __restrict__ idx_f,           // f32 idx output
              const int Nt)
{
    __shared__ __align__(16) float Asm[128 * 64];
    __shared__ __align__(16) float Bsm[128 * 64];
    const int tid = threadIdx.x;
    const int tx = tid & 15, ty = tid >> 4;
    const int tokbase = blockIdx.x * 128;
    const float* CBs = cb + (size_t)SC * K_CODES * D_DIM;

    // preload prev-stage indices for my 8 staging rows (static-indexed)
    int kprev[SC > 0 ? SC : 1][8];
    #pragma unroll
    for (int p = 0; p < SC; ++p)
        #pragma unroll
        for (int i = 0; i < 8; ++i)
            kprev[p][i] = idx_ws[(size_t)p * Nt + tokbase + i * 16 + ty];

    float best[8];
    int besti[8];
    #pragma unroll
    for (int m = 0; m < 8; ++m) { best[m] = 3.4e38f; besti[m] = 0; }

    float acc[8][8];

    for (int kt = 0; kt < 8; ++kt) {
        #pragma unroll
        for (int m = 0; m < 8; ++m)
            #pragma unroll
            for (int u = 0; u < 8; ++u) acc[m][u] = 0.0f;

        for (int dc = 0; dc < 4; ++dc) {
            const int dbase = dc * 64;
            __syncthreads();
            #pragma unroll
            for (int i = 0; i < 8; ++i) {
                const int row = i * 16 + ty;
                const int sw = (row >> 3) & 7;
                float4 va = *(const float4*)(z + (size_t)(tokbase + row) * D_DIM + dbase + tx * 4);
                #pragma unroll
                for (int p = 0; p < SC; ++p) {
                    const float4 q = *(const float4*)(cb + ((size_t)p * K_CODES + kprev[p][i]) * D_DIM + dbase + tx * 4);
                    va.x -= q.x; va.y -= q.y; va.z -= q.z; va.w -= q.w;
                }
                *(float4*)(Asm + row * 64 + ((tx ^ sw) << 2)) = va;
                const float4 vb = *(const float4*)(CBs + (size_t)(kt * 128 + row) * D_DIM + dbase + tx * 4);
                *(float4*)(Bsm + row * 64 + ((tx ^ sw) << 2)) = vb;
            }
            __syncthreads();
            const int sa = ty & 7;
            const int sb = tx & 7;
            #pragma unroll 1
            for (int ds = 0; ds < 16; ++ds) {
                float4 a4[8], b4[8];
                const int oa = (ds ^ sa) << 2;
                const int ob = (ds ^ sb) << 2;
                #pragma unroll
                for (int m = 0; m < 8; ++m)
                    a4[m] = *(const float4*)(Asm + (ty * 8 + m) * 64 + oa);
                #pragma unroll
                for (int u = 0; u < 8; ++u)
                    b4[u] = *(const float4*)(Bsm + (tx * 8 + u) * 64 + ob);
                #pragma unroll
                for (int m = 0; m < 8; ++m) {
                    #pragma unroll
                    for (int u = 0; u < 8; ++u) {
                        float s = acc[m][u];
                        s = fmaf(a4[m].x, b4[u].x, s);
                        s = fmaf(a4[m].y, b4[u].y, s);
                        s = fmaf(a4[m].z, b4[u].z, s);
                        s = fmaf(a4[m].w, b4[u].w, s);
                        acc[m][u] = s;
                    }
                }
            }
        }
        #pragma unroll
        for (int u = 0; u < 8; ++u) {
            const int k = kt * 128 + tx * 8 + u;
            const float ss = sumsq_s[k];
            #pragma unroll
            for (int m = 0; m < 8; ++m) {
                const float dist = ss - 2.0f * acc[m][u];
                if (dist < best[m] || (dist == best[m] && k < besti[m])) {
                    best[m] = dist; besti[m] = k;
                }
            }
        }
    }

    __syncthreads();
    float* rd = Asm;            // [128][16]
    int* ri = (int*)Bsm;        // [128][16]
    #pragma unroll
    for (int m = 0; m < 8; ++m) {
        rd[(ty * 8 + m) * 16 + tx] = best[m];
        ri[(ty * 8 + m) * 16 + tx] = besti[m];
    }
    __syncthreads();
    if (tid < 128) {
        float bd = rd[tid * 16];
        int bi = ri[tid * 16];
        #pragma unroll
        for (int j = 1; j < 16; ++j) {
            const float dd = rd[tid * 16 + j];
            const int ii = ri[tid * 16 + j];
            if (dd < bd || (dd == bd && ii < bi)) { bd = dd; bi = ii; }
        }
        const int n = tokbase + tid;
        idx_int[n] = bi;
        idx_f[n] = (float)bi;
    }
}

// ---------- EMA partials: 64 kgroups x NSPLIT token-splits, residual recomputed ----------
template<int SC>
__global__ void k_ema_partial(const float* __restrict__ z,
                              const float* __restrict__ cb,
                              const int* __restrict__ idx_ws,
                              float* __restrict__ partial,   // [NSPLIT][K][D]
                              float* __restrict__ counts,    // [NSPLIT][K]
                              const int Nt)
{
    const int b = blockIdx.x;
    const int kg = b & 63;
    const int ns = b >> 6;
    const int kbase = kg * 16;
    const int t = threadIdx.x;
    const int tok_per_split = Nt / NSPLIT;
    const int nbase = ns * tok_per_split;
    const int* idx_s = idx_ws + (size_t)SC * Nt;

    float acc[16];
    #pragma unroll
    for (int j = 0; j < 16; ++j) acc[j] = 0.0f;
    float cnt = 0.0f;

    const int4* idx4 = (const int4*)(idx_s + nbase);
    const int iters = tok_per_split >> 2;
    for (int ii = 0; ii < iters; ++ii) {
        const int4 kv = idx4[ii];
        const int ks4[4] = {kv.x, kv.y, kv.z, kv.w};
        #pragma unroll
        for (int c = 0; c < 4; ++c) {
            const unsigned local = (unsigned)(ks4[c] - kbase);
            if (local < 16u) {
                const int n = nbase + ii * 4 + c;
                float v = z[(size_t)n * D_DIM + t];
                #pragma unroll
                for (int p = 0; p < SC; ++p) {
                    const int kp = idx_ws[(size_t)p * Nt + n];
                    v -= cb[((size_t)p * K_CODES + kp) * D_DIM + t];
                }
                #pragma unroll
                for (int j = 0; j < 16; ++j) acc[j] += (local == (unsigned)j) ? v : 0.0f;
                cnt += ((unsigned)t == local) ? 1.0f : 0.0f;
            }
        }
    }
    #pragma unroll
    for (int j = 0; j < 16; ++j)
        partial[((size_t)ns * K_CODES + kbase + j) * D_DIM + t] = acc[j];
    if (t < 16) counts[ns * K_CODES + kbase + t] = cnt;
}

__global__ void k_ema_final(const float* __restrict__ partial,
                            const float* __restrict__ counts,
                            const float* __restrict__ N_in,     // + s*K
                            const float* __restrict__ zavg_in,  // + s*K*D
                            float* __restrict__ out_N,
                            float* __restrict__ out_zavg,
                            float* __restrict__ out_cb)
{
    const int k = blockIdx.x;
    const int t = threadIdx.x;
    float zsum = 0.0f;
    #pragma unroll
    for (int ns = 0; ns < NSPLIT; ++ns) zsum += partial[((size_t)ns * K_CODES + k) * D_DIM + t];
    float cnt = 0.0f;
    #pragma unroll
    for (int ns = 0; ns < NSPLIT; ++ns) cnt += counts[ns * K_CODES + k];
    const float zk = zsum / (cnt + EPS_F);
    const float Ns = DECAY * N_in[k] + (1.0f - DECAY) * cnt;
    const float za = DECAY * zavg_in[(size_t)k * D_DIM + t] + (1.0f - DECAY) * zk;
    const float cbn = za / (Ns + EPS_F);
    out_zavg[(size_t)k * D_DIM + t] = za;
    out_cb[(size_t)k * D_DIM + t] = cbn;
    if (t == 0) out_N[k] = Ns;
}

// ---------- fused recon + all per-stage losses ----------
__global__ void k_recon_loss(const float* __restrict__ z,
                             const float* __restrict__ cb,
                             const int* __restrict__ idx_ws,
                             float* __restrict__ out_zq,
                             float* __restrict__ lossa,
                             const int total4, const int Nt)
{
    float lp0 = 0.f, lp1 = 0.f, lp2 = 0.f, lp3 = 0.f;
    for (int i = blockIdx.x * blockDim.x + threadIdx.x; i < total4; i += gridDim.x * blockDim.x) {
        const int n = i >> 6;
        const int c = (i & 63) << 2;
        const float4 zv = *(const float4*)(z + (size_t)n * D_DIM + c);
        float rx = zv.x, ry = zv.y, rz = zv.z, rw = zv.w;
        float ax = 0.f, ay = 0.f, az = 0.f, aw = 0.f;
        #pragma unroll
        for (int s = 0; s < S_STAGES; ++s) {
            const int k = idx_ws[(size_t)s * Nt + n];
            const float4 q = *(const float4*)(cb + ((size_t)s * K_CODES + k) * D_DIM + c);
            const float dx = q.x - rx, dy = q.y - ry, dz = q.z - rz, dw = q.w - rw;
            const float l = dx * dx + dy * dy + dz * dz + dw * dw;
            if (s == 0) lp0 += l; else if (s == 1) lp1 += l; else if (s == 2) lp2 += l; else lp3 += l;
            ax += q.x; ay += q.y; az += q.z; aw += q.w;
            rx -= q.x; ry -= q.y; rz -= q.z; rw -= q.w;
        }
        float4 o;
        o.x = zv.x + (ax - zv.x);
        o.y = zv.y + (ay - zv.y);
        o.z = zv.z + (az - zv.z);
        o.w = zv.w + (aw - zv.w);
        *(float4*)(out_zq + (size_t)n * D_DIM + c) = o;
    }
    #pragma unroll
    for (int off = 32; off > 0; off >>= 1) {
        lp0 += __shfl_down(lp0, off, 64);
        lp1 += __shfl_down(lp1, off, 64);
        lp2 += __shfl_down(lp2, off, 64);
        lp3 += __shfl_down(lp3, off, 64);
    }
    __shared__ float wsum[4][4];
    const int lane = threadIdx.x & 63, w = threadIdx.x >> 6;
    if (lane == 0) { wsum[w][0] = lp0; wsum[w][1] = lp1; wsum[w][2] = lp2; wsum[w][3] = lp3; }
    __syncthreads();
    if (threadIdx.x == 0) {
        #pragma unroll
        for (int s = 0; s < 4; ++s)
            atomicAdd(lossa + s, (wsum[0][s] + wsum[1][s]) + (wsum[2][s] + wsum[3][s]));
    }
}

__global__ void k_loss_final(const float* __restrict__ loss_acc,
                             float* __restrict__ out_loss,
                             const float meanDiv)
{
    if (threadIdx.x == 0 && blockIdx.x == 0) {
        float loss = 0.0f;
        #pragma unroll
        for (int s = 0; s < S_STAGES; ++s) loss = loss + BETA * (loss_acc[s] / meanDiv);
        out_loss[0] = loss;
    }
}

extern "C" void kernel_launch(void* const* d_in, const int* in_sizes, int n_in,
                              void* d_out, int out_size, void* d_ws, size_t ws_size,
                              hipStream_t stream)
{
    const float* z = (const float*)d_in[0];
    const float* cb = (const float*)d_in[1];
    const float* N_in = (const float*)d_in[2];
    const float* zavg = (const float*)d_in[3];
    float* out = (float*)d_out;               // fp32 outputs (reference dtype)

    const int Nt = in_sizes[0] / D_DIM;      // 65536
    const int total4 = Nt * (D_DIM / 4);

    // workspace layout (~9.1 MB total)
    int* idx_ws = (int*)d_ws;                                    // S*Nt
    float* sumsq = (float*)(idx_ws + (size_t)S_STAGES * Nt);     // S*K
    float* lossa = sumsq + S_STAGES * K_CODES;                   // 16 (4 used)
    float* partial = lossa + 16;                                 // NSPLIT*K*D
    float* counts = partial + (size_t)NSPLIT * K_CODES * D_DIM;  // NSPLIT*K

    const size_t ZQ_OFF = 0;
    const size_t LOSS_OFF = (size_t)Nt * D_DIM;
    const size_t IDX_OFF = LOSS_OFF + 1;
    const size_t CB_OFF = IDX_OFF + (size_t)S_STAGES * Nt;
    const size_t N_OFF = CB_OFF + (size_t)S_STAGES * K_CODES * D_DIM;
    const size_t ZAVG_OFF = N_OFF + (size_t)S_STAGES * K_CODES;

    hipMemsetAsync(lossa, 0, 16 * sizeof(float), stream);
    k_sumsq<<<(S_STAGES * K_CODES + 255) / 256, 256, 0, stream>>>(cb, sumsq);

    for (int s = 0; s < S_STAGES; ++s) {
        int* idx_int = idx_ws + (size_t)s * Nt;
        float* idx_f = out + IDX_OFF + (size_t)s * Nt;
        const float* ss_s = sumsq + s * K_CODES;
        switch (s) {
        case 0:
            k_argmin<0><<<Nt / 128, 256, 0, stream>>>(z, cb, idx_ws, ss_s, idx_int, idx_f, Nt);
            k_ema_partial<0><<<64 * NSPLIT, 256, 0, stream>>>(z, cb, idx_ws, partial, counts, Nt);
            break;
        case 1:
            k_argmin<1><<<Nt / 128, 256, 0, stream>>>(z, cb, idx_ws, ss_s, idx_int, idx_f, Nt);
            k_ema_partial<1><<<64 * NSPLIT, 256, 0, stream>>>(z, cb, idx_ws, partial, counts, Nt);
            break;
        case 2:
            k_argmin<2><<<Nt / 128, 256, 0, stream>>>(z, cb, idx_ws, ss_s, idx_int, idx_f, Nt);
            k_ema_partial<2><<<64 * NSPLIT, 256, 0, stream>>>(z, cb, idx_ws, partial, counts, Nt);
            break;
        default:
            k_argmin<3><<<Nt / 128, 256, 0, stream>>>(z, cb, idx_ws, ss_s, idx_int, idx_f, Nt);
            k_ema_partial<3><<<64 * NSPLIT, 256, 0, stream>>>(z, cb, idx_ws, partial, counts, Nt);
            break;
        }
        k_ema_final<<<K_CODES, 256, 0, stream>>>(
            partial, counts, N_in + s * K_CODES, zavg + (size_t)s * K_CODES * D_DIM,
            out + N_OFF + s * K_CODES,
            out + ZAVG_OFF + (size_t)s * K_CODES * D_DIM,
            out + CB_OFF + (size_t)s * K_CODES * D_DIM);
    }
    k_recon_loss<<<2048, 256, 0, stream>>>(z, cb, idx_ws, out + ZQ_OFF, lossa, total4, Nt);
    k_loss_final<<<1, 64, 0, stream>>>(lossa, out + LOSS_OFF, (float)((size_t)Nt * D_DIM));
}

// Round 5
// 2830.984 us; speedup vs baseline: 1.2250x; 1.2250x over previous
//
#include <hip/hip_runtime.h>

#define D_DIM 256
#define K_CODES 1024
#define S_STAGES 4
#define BETA 0.25f
#define DECAY 0.99f
#define EPS_F 1e-5f
#define LDSW 40   // padded row stride (elems) for 32-elem chunks: 80B rows, odd 16B-granule stride

typedef float f32x4 __attribute__((ext_vector_type(4)));
typedef short s16x8 __attribute__((ext_vector_type(8)));

__device__ __forceinline__ unsigned short f2bf(float f) {
    unsigned u = __float_as_uint(f);
    unsigned r = u + 0x7fffu + ((u >> 16) & 1u);
    return (unsigned short)(r >> 16);
}
__device__ __forceinline__ float bf2f(unsigned short u) {
    return __uint_as_float(((unsigned)u) << 16);
}
__device__ __forceinline__ void split3(float x, unsigned short& h, unsigned short& m, unsigned short& l) {
    h = f2bf(x);
    float r1 = x - bf2f(h);
    m = f2bf(r1);
    float r2 = r1 - bf2f(m);
    l = f2bf(r2);
}

// ---------- sum of squares per code row (numpy pairwise order) ----------
__global__ void k_sumsq(const float* __restrict__ cb, float* __restrict__ out) {
    #pragma clang fp contract(off)
    int i = blockIdx.x * blockDim.x + threadIdx.x;
    if (i >= S_STAGES * K_CODES) return;
    const float* p = cb + (size_t)i * D_DIM;
    float tot = 0.0f;
    for (int h = 0; h < 256; h += 128) {
        const float* q = p + h;
        float r[8];
        #pragma unroll
        for (int j = 0; j < 8; ++j) { float v = q[j]; r[j] = v * v; }
        for (int t = 8; t < 128; t += 8) {
            #pragma unroll
            for (int j = 0; j < 8; ++j) { float v = q[t + j]; r[j] = r[j] + v * v; }
        }
        float res = ((r[0] + r[1]) + (r[2] + r[3])) + ((r[4] + r[5]) + (r[6] + r[7]));
        tot = tot + res;
    }
    out[i] = tot;
}

// ---------- precompute codebook 3-term bf16 splits, layout [S][8 dc][K][32] ----------
__global__ void k_splitB(const float* __restrict__ cb,
                         unsigned short* __restrict__ Bh,
                         unsigned short* __restrict__ Bm,
                         unsigned short* __restrict__ Bl) {
    const int TOT = S_STAGES * K_CODES * D_DIM;
    for (int e = blockIdx.x * blockDim.x + threadIdx.x; e < TOT; e += gridDim.x * blockDim.x) {
        int s = e >> 18, k = (e >> 8) & 1023, d = e & 255;
        float x = cb[e];
        unsigned short h, m, l;
        split3(x, h, m, l);
        size_t o = ((((size_t)s * 8 + (d >> 5)) * K_CODES) + k) * 32 + (d & 31);
        Bh[o] = h; Bm[o] = m; Bl[o] = l;
    }
}

// ---------- MFMA argmin: 128 tokens x 1024 codes per block ----------
__global__ __launch_bounds__(256, 2)
void k_argmin_mfma(const float* __restrict__ Rsrc,
                   const unsigned short* __restrict__ Bh,
                   const unsigned short* __restrict__ Bm,
                   const unsigned short* __restrict__ Bl,
                   const float* __restrict__ ss_s,
                   const int sidx,
                   int* __restrict__ idx_int,
                   float* __restrict__ idx_f)
{
    __shared__ __align__(16) unsigned short Ap0[128 * LDSW];
    __shared__ __align__(16) unsigned short Ap1[128 * LDSW];
    __shared__ __align__(16) unsigned short Ap2[128 * LDSW];
    __shared__ __align__(16) unsigned short Bp0[128 * LDSW];
    __shared__ __align__(16) unsigned short Bp1[128 * LDSW];
    __shared__ __align__(16) unsigned short Bp2[128 * LDSW];
    __shared__ float redD[128];
    __shared__ int   redI[128];

    const int tid = threadIdx.x;
    const int lane = tid & 63, w = tid >> 6;
    const int wr = w >> 1, wc = w & 1;
    const int r15 = lane & 15, g = lane >> 4;
    const int tokbase = blockIdx.x * 128;

    const int arow = tid & 127, ah = tid >> 7;   // A staging: 2 threads/row, 16 floats each
    const int brow = tid >> 1,  bhh = tid & 1;   // B staging: 2 threads/row, 16 bf16 each

    float best[4][4];
    int   besti[4][4];
    #pragma unroll
    for (int mt = 0; mt < 4; ++mt)
        #pragma unroll
        for (int j = 0; j < 4; ++j) { best[mt][j] = 3.4e38f; besti[mt][j] = 0; }

    for (int kt = 0; kt < 8; ++kt) {
        f32x4 acc[4][4];
        #pragma unroll
        for (int mt = 0; mt < 4; ++mt)
            #pragma unroll
            for (int nt = 0; nt < 4; ++nt) acc[mt][nt] = (f32x4){0.f, 0.f, 0.f, 0.f};

        for (int dc = 0; dc < 8; ++dc) {
            __syncthreads();
            // ---- stage A: read 16 fp32 of residual, 3-term split, write LDS ----
            {
                const float4* asrc = (const float4*)(Rsrc + (size_t)(tokbase + arow) * D_DIM + dc * 32 + ah * 16);
                float xs[16];
                float4 t0 = asrc[0], t1 = asrc[1], t2 = asrc[2], t3 = asrc[3];
                xs[0]=t0.x; xs[1]=t0.y; xs[2]=t0.z; xs[3]=t0.w;
                xs[4]=t1.x; xs[5]=t1.y; xs[6]=t1.z; xs[7]=t1.w;
                xs[8]=t2.x; xs[9]=t2.y; xs[10]=t2.z; xs[11]=t2.w;
                xs[12]=t3.x; xs[13]=t3.y; xs[14]=t3.z; xs[15]=t3.w;
                unsigned wh[8], wm[8], wl[8];
                #pragma unroll
                for (int j = 0; j < 8; ++j) {
                    unsigned short h0, m0, l0, h1, m1, l1;
                    split3(xs[2*j],   h0, m0, l0);
                    split3(xs[2*j+1], h1, m1, l1);
                    wh[j] = (unsigned)h0 | ((unsigned)h1 << 16);
                    wm[j] = (unsigned)m0 | ((unsigned)m1 << 16);
                    wl[j] = (unsigned)l0 | ((unsigned)l1 << 16);
                }
                const int o = arow * LDSW + ah * 16;
                uint4* d0 = (uint4*)&Ap0[o];
                d0[0] = (uint4){wh[0], wh[1], wh[2], wh[3]};
                d0[1] = (uint4){wh[4], wh[5], wh[6], wh[7]};
                uint4* d1 = (uint4*)&Ap1[o];
                d1[0] = (uint4){wm[0], wm[1], wm[2], wm[3]};
                d1[1] = (uint4){wm[4], wm[5], wm[6], wm[7]};
                uint4* d2 = (uint4*)&Ap2[o];
                d2[0] = (uint4){wl[0], wl[1], wl[2], wl[3]};
                d2[1] = (uint4){wl[4], wl[5], wl[6], wl[7]};
            }
            // ---- stage B: copy precomputed splits ----
            {
                const size_t gbase = ((((size_t)sidx * 8 + dc) * K_CODES) + kt * 128 + brow) * 32 + bhh * 16;
                const int o = brow * LDSW + bhh * 16;
                {
                    const uint4* s4 = (const uint4*)(Bh + gbase);
                    uint4* d4 = (uint4*)&Bp0[o]; d4[0] = s4[0]; d4[1] = s4[1];
                }
                {
                    const uint4* s4 = (const uint4*)(Bm + gbase);
                    uint4* d4 = (uint4*)&Bp1[o]; d4[0] = s4[0]; d4[1] = s4[1];
                }
                {
                    const uint4* s4 = (const uint4*)(Bl + gbase);
                    uint4* d4 = (uint4*)&Bp2[o]; d4[0] = s4[0]; d4[1] = s4[1];
                }
            }
            __syncthreads();

            // ---- fragments + 96 MFMA ----
            s16x8 a0[4], a1[4], a2[4], bb[4];
            #pragma unroll
            for (int mt = 0; mt < 4; ++mt) {
                const int o = (wr * 64 + mt * 16 + r15) * LDSW + g * 8;
                a0[mt] = *(const s16x8*)&Ap0[o];
                a1[mt] = *(const s16x8*)&Ap1[o];
                a2[mt] = *(const s16x8*)&Ap2[o];
            }
            // group B=hi: A in {h,m,l}
            #pragma unroll
            for (int nt = 0; nt < 4; ++nt)
                bb[nt] = *(const s16x8*)&Bp0[(wc * 64 + nt * 16 + r15) * LDSW + g * 8];
            #pragma unroll
            for (int mt = 0; mt < 4; ++mt)
                #pragma unroll
                for (int nt = 0; nt < 4; ++nt)
                    acc[mt][nt] = __builtin_amdgcn_mfma_f32_16x16x32_bf16(a0[mt], bb[nt], acc[mt][nt], 0, 0, 0);
            #pragma unroll
            for (int mt = 0; mt < 4; ++mt)
                #pragma unroll
                for (int nt = 0; nt < 4; ++nt)
                    acc[mt][nt] = __builtin_amdgcn_mfma_f32_16x16x32_bf16(a1[mt], bb[nt], acc[mt][nt], 0, 0, 0);
            #pragma unroll
            for (int mt = 0; mt < 4; ++mt)
                #pragma unroll
                for (int nt = 0; nt < 4; ++nt)
                    acc[mt][nt] = __builtin_amdgcn_mfma_f32_16x16x32_bf16(a2[mt], bb[nt], acc[mt][nt], 0, 0, 0);
            // group B=mid: A in {h,m}
            #pragma unroll
            for (int nt = 0; nt < 4; ++nt)
                bb[nt] = *(const s16x8*)&Bp1[(wc * 64 + nt * 16 + r15) * LDSW + g * 8];
            #pragma unroll
            for (int mt = 0; mt < 4; ++mt)
                #pragma unroll
                for (int nt = 0; nt < 4; ++nt)
                    acc[mt][nt] = __builtin_amdgcn_mfma_f32_16x16x32_bf16(a0[mt], bb[nt], acc[mt][nt], 0, 0, 0);
            #pragma unroll
            for (int mt = 0; mt < 4; ++mt)
                #pragma unroll
                for (int nt = 0; nt < 4; ++nt)
                    acc[mt][nt] = __builtin_amdgcn_mfma_f32_16x16x32_bf16(a1[mt], bb[nt], acc[mt][nt], 0, 0, 0);
            // group B=lo: A in {h}
            #pragma unroll
            for (int nt = 0; nt < 4; ++nt)
                bb[nt] = *(const s16x8*)&Bp2[(wc * 64 + nt * 16 + r15) * LDSW + g * 8];
            #pragma unroll
            for (int mt = 0; mt < 4; ++mt)
                #pragma unroll
                for (int nt = 0; nt < 4; ++nt)
                    acc[mt][nt] = __builtin_amdgcn_mfma_f32_16x16x32_bf16(a0[mt], bb[nt], acc[mt][nt], 0, 0, 0);
        }

        // ---- epilogue: dist = ss - 2*dot, running first-min (k ascending) ----
        #pragma unroll
        for (int nt = 0; nt < 4; ++nt) {
            const int kcol = kt * 128 + wc * 64 + nt * 16 + r15;
            const float ssv = ss_s[kcol];
            #pragma unroll
            for (int mt = 0; mt < 4; ++mt) {
                #pragma unroll
                for (int j = 0; j < 4; ++j) {
                    const float dist = ssv - 2.0f * acc[mt][nt][j];
                    if (dist < best[mt][j]) { best[mt][j] = dist; besti[mt][j] = kcol; }
                }
            }
        }
    }

    // ---- reduce over the 16 col-lanes within each warp ----
    float rbd[4][4];
    int   rbi[4][4];
    #pragma unroll
    for (int mt = 0; mt < 4; ++mt) {
        #pragma unroll
        for (int j = 0; j < 4; ++j) {
            float bd = best[mt][j];
            int bi = besti[mt][j];
            #pragma unroll
            for (int mm = 1; mm <= 8; mm <<= 1) {
                const float od = __shfl_xor(bd, mm, 64);
                const int oi = __shfl_xor(bi, mm, 64);
                if (od < bd || (od == bd && oi < bi)) { bd = od; bi = oi; }
            }
            rbd[mt][j] = bd; rbi[mt][j] = bi;
        }
    }
    // ---- cross-warp combine: wc==1 deposits, wc==0 merges + writes ----
    __syncthreads();
    #pragma unroll
    for (int mt = 0; mt < 4; ++mt)
        #pragma unroll
        for (int j = 0; j < 4; ++j)
            if (wc == 1 && r15 == 0) {
                const int trow = wr * 64 + mt * 16 + g * 4 + j;
                redD[trow] = rbd[mt][j];
                redI[trow] = rbi[mt][j];
            }
    __syncthreads();
    #pragma unroll
    for (int mt = 0; mt < 4; ++mt)
        #pragma unroll
        for (int j = 0; j < 4; ++j)
            if (wc == 0 && r15 == 0) {
                const int trow = wr * 64 + mt * 16 + g * 4 + j;
                float bd = rbd[mt][j];
                int bi = rbi[mt][j];
                const float od = redD[trow];
                const int oi = redI[trow];
                if (od < bd || (od == bd && oi < bi)) { bd = od; bi = oi; }
                const int n = tokbase + trow;
                idx_int[n] = bi;
                idx_f[n] = (float)bi;
            }
}

// ---------- counting sort: histogram ----------
__global__ void k_hist(const int* __restrict__ idx_s, int* __restrict__ hist, const int Nt) {
    __shared__ int lh[K_CODES];
    for (int i = threadIdx.x; i < K_CODES; i += blockDim.x) lh[i] = 0;
    __syncthreads();
    for (int n = blockIdx.x * blockDim.x + threadIdx.x; n < Nt; n += gridDim.x * blockDim.x)
        atomicAdd(&lh[idx_s[n]], 1);
    __syncthreads();
    for (int i = threadIdx.x; i < K_CODES; i += blockDim.x)
        if (lh[i]) atomicAdd(&hist[i], lh[i]);
}

// ---------- prefix sum over 1024 bins (1 block, 256 threads) ----------
__global__ void k_scan(const int* __restrict__ hist, int* __restrict__ off,
                       int* __restrict__ cursor) {
    __shared__ int tsum[256];
    const int t = threadIdx.x;
    int v[4], s = 0;
    #pragma unroll
    for (int j = 0; j < 4; ++j) { v[j] = hist[t * 4 + j]; s += v[j]; }
    tsum[t] = s;
    __syncthreads();
    if (t == 0) {
        int run = 0;
        for (int i = 0; i < 256; ++i) { int x = tsum[i]; tsum[i] = run; run += x; }
    }
    __syncthreads();
    int run = tsum[t];
    #pragma unroll
    for (int j = 0; j < 4; ++j) {
        off[t * 4 + j] = run;
        cursor[t * 4 + j] = run;
        run += v[j];
    }
    if (t == 255) off[K_CODES] = run;
}

// ---------- scatter tokens into per-code lists ----------
__global__ void k_scatter(const int* __restrict__ idx_s, int* __restrict__ cursor,
                          int* __restrict__ perm, const int Nt) {
    for (int n = blockIdx.x * blockDim.x + threadIdx.x; n < Nt; n += gridDim.x * blockDim.x) {
        const int pos = atomicAdd(&cursor[idx_s[n]], 1);
        perm[pos] = n;
    }
}

// ---------- per-code segment sum + EMA finalize ----------
__global__ void k_codesum(const float* __restrict__ Rsrc,
                          const int* __restrict__ off, const int* __restrict__ perm,
                          const float* __restrict__ N_in, const float* __restrict__ zavg_in,
                          float* __restrict__ out_N, float* __restrict__ out_zavg,
                          float* __restrict__ out_cb) {
    const int k = blockIdx.x, t = threadIdx.x;
    const int s0 = off[k], s1 = off[k + 1];
    float acc = 0.0f;
    for (int m = s0; m < s1; ++m) {
        const int n = perm[m];
        acc += Rsrc[(size_t)n * D_DIM + t];
    }
    const float cnt = (float)(s1 - s0);
    const float zk = acc / (cnt + EPS_F);
    const float Ns = DECAY * N_in[k] + (1.0f - DECAY) * cnt;
    const float za = DECAY * zavg_in[(size_t)k * D_DIM + t] + (1.0f - DECAY) * zk;
    out_zavg[(size_t)k * D_DIM + t] = za;
    out_cb[(size_t)k * D_DIM + t] = za / (Ns + EPS_F);
    if (t == 0) out_N[k] = Ns;
}

// ---------- residual update + per-stage loss (mode 1: final stage writes z_q) ----------
__global__ void k_resid(const float* __restrict__ Rsrc, const float* __restrict__ z,
                        const float* __restrict__ cb_s, const int* __restrict__ idx_s,
                        float* __restrict__ Rdst, float* __restrict__ out_zq,
                        float* __restrict__ loss_s, const int mode, const int total4) {
    float lp = 0.0f;
    for (int i = blockIdx.x * blockDim.x + threadIdx.x; i < total4; i += gridDim.x * blockDim.x) {
        const int n = i >> 6;
        const int c = (i & 63) << 2;
        const int k = idx_s[n];
        const float4 r = *(const float4*)(Rsrc + (size_t)n * D_DIM + c);
        const float4 q = *(const float4*)(cb_s + (size_t)k * D_DIM + c);
        const float dx = q.x - r.x, dy = q.y - r.y, dz = q.z - r.z, dw = q.w - r.w;
        lp += dx * dx + dy * dy + dz * dz + dw * dw;
        if (mode == 0) {
            float4 o;
            o.x = r.x - q.x; o.y = r.y - q.y; o.z = r.z - q.z; o.w = r.w - q.w;
            *(float4*)(Rdst + (size_t)n * D_DIM + c) = o;
        } else {
            const float4 zv = *(const float4*)(z + (size_t)n * D_DIM + c);
            float4 o;
            o.x = (zv.x - r.x) + q.x;
            o.y = (zv.y - r.y) + q.y;
            o.z = (zv.z - r.z) + q.z;
            o.w = (zv.w - r.w) + q.w;
            *(float4*)(out_zq + (size_t)n * D_DIM + c) = o;
        }
    }
    #pragma unroll
    for (int offs = 32; offs > 0; offs >>= 1) lp += __shfl_down(lp, offs, 64);
    __shared__ float wsum[4];
    const int lane = threadIdx.x & 63, w = threadIdx.x >> 6;
    if (lane == 0) wsum[w] = lp;
    __syncthreads();
    if (threadIdx.x == 0) atomicAdd(loss_s, (wsum[0] + wsum[1]) + (wsum[2] + wsum[3]));
}

__global__ void k_loss_final(const float* __restrict__ loss_acc,
                             float* __restrict__ out_loss, const float meanDiv) {
    if (threadIdx.x == 0 && blockIdx.x == 0) {
        float loss = 0.0f;
        #pragma unroll
        for (int s = 0; s < S_STAGES; ++s) loss = loss + BETA * (loss_acc[s] / meanDiv);
        out_loss[0] = loss;
    }
}

extern "C" void kernel_launch(void* const* d_in, const int* in_sizes, int n_in,
                              void* d_out, int out_size, void* d_ws, size_t ws_size,
                              hipStream_t stream)
{
    const float* z = (const float*)d_in[0];
    const float* cb = (const float*)d_in[1];
    const float* N_in = (const float*)d_in[2];
    const float* zavg = (const float*)d_in[3];
    float* out = (float*)d_out;

    const int Nt = in_sizes[0] / D_DIM;      // 65536
    const int total4 = Nt * (D_DIM / 4);

    // ---- workspace layout (~71.3 MB) ----
    char* wp = (char*)d_ws;
    int* idx_ws = (int*)wp;                 wp += (size_t)S_STAGES * Nt * 4;
    int* perm   = (int*)wp;                 wp += (size_t)Nt * 4;
    int* hist   = (int*)wp;                 wp += K_CODES * 4;
    int* cursor = (int*)wp;                 wp += K_CODES * 4;
    int* off    = (int*)wp;                 wp += (K_CODES + 8) * 4;
    float* sumsq = (float*)wp;              wp += S_STAGES * K_CODES * 4;
    float* lossa = (float*)wp;              wp += 64;
    unsigned short* Bh = (unsigned short*)wp; wp += (size_t)S_STAGES * K_CODES * D_DIM * 2;
    unsigned short* Bm = (unsigned short*)wp; wp += (size_t)S_STAGES * K_CODES * D_DIM * 2;
    unsigned short* Bl = (unsigned short*)wp; wp += (size_t)S_STAGES * K_CODES * D_DIM * 2;
    wp = (char*)(((size_t)wp + 255) & ~(size_t)255);
    float* Rbuf = (float*)wp;               // Nt * D fp32 (64 MB)

    const size_t ZQ_OFF = 0;
    const size_t LOSS_OFF = (size_t)Nt * D_DIM;
    const size_t IDX_OFF = LOSS_OFF + 1;
    const size_t CB_OFF = IDX_OFF + (size_t)S_STAGES * Nt;
    const size_t N_OFF = CB_OFF + (size_t)S_STAGES * K_CODES * D_DIM;
    const size_t ZAVG_OFF = N_OFF + (size_t)S_STAGES * K_CODES;

    hipMemsetAsync(lossa, 0, 64, stream);
    k_sumsq<<<(S_STAGES * K_CODES + 255) / 256, 256, 0, stream>>>(cb, sumsq);
    k_splitB<<<1024, 256, 0, stream>>>(cb, Bh, Bm, Bl);

    for (int s = 0; s < S_STAGES; ++s) {
        const float* Rsrc = (s == 0) ? z : Rbuf;
        int* idx_s = idx_ws + (size_t)s * Nt;
        k_argmin_mfma<<<Nt / 128, 256, 0, stream>>>(
            Rsrc, Bh, Bm, Bl, sumsq + s * K_CODES, s,
            idx_s, out + IDX_OFF + (size_t)s * Nt);
        hipMemsetAsync(hist, 0, K_CODES * 4, stream);
        k_hist<<<64, 256, 0, stream>>>(idx_s, hist, Nt);
        k_scan<<<1, 256, 0, stream>>>(hist, off, cursor);
        k_scatter<<<64, 256, 0, stream>>>(idx_s, cursor, perm, Nt);
        k_codesum<<<K_CODES, 256, 0, stream>>>(
            Rsrc, off, perm,
            N_in + s * K_CODES, zavg + (size_t)s * K_CODES * D_DIM,
            out + N_OFF + s * K_CODES,
            out + ZAVG_OFF + (size_t)s * K_CODES * D_DIM,
            out + CB_OFF + (size_t)s * K_CODES * D_DIM);
        k_resid<<<2048, 256, 0, stream>>>(
            Rsrc, z, cb + (size_t)s * K_CODES * D_DIM, idx_s,
            Rbuf, out + ZQ_OFF, lossa + s, (s == 3) ? 1 : 0, total4);
    }
    k_loss_final<<<1, 64, 0, stream>>>(lossa, out + LOSS_OFF, (float)((size_t)Nt * D_DIM));
}

// Round 6
// 1245.184 us; speedup vs baseline: 2.7851x; 2.2735x over previous
//
#include <hip/hip_runtime.h>

#define D_DIM 256
#define K_CODES 1024
#define S_STAGES 4
#define BETA 0.25f
#define DECAY 0.99f
#define EPS_F 1e-5f
#define LDSW 40   // padded row stride (elems) for 32-elem chunks: 80B rows, odd 16B-granule stride
#define CHUNK 64  // tokens per chunksum block

typedef float f32x4 __attribute__((ext_vector_type(4)));
typedef short s16x8 __attribute__((ext_vector_type(8)));

__device__ __forceinline__ unsigned short f2bf(float f) {
    unsigned u = __float_as_uint(f);
    unsigned r = u + 0x7fffu + ((u >> 16) & 1u);
    return (unsigned short)(r >> 16);
}
__device__ __forceinline__ float bf2f(unsigned short u) {
    return __uint_as_float(((unsigned)u) << 16);
}
__device__ __forceinline__ void split3(float x, unsigned short& h, unsigned short& m, unsigned short& l) {
    h = f2bf(x);
    float r1 = x - bf2f(h);
    m = f2bf(r1);
    float r2 = r1 - bf2f(m);
    l = f2bf(r2);
}

// ---------- sum of squares per code row (numpy pairwise order) ----------
__global__ void k_sumsq(const float* __restrict__ cb, float* __restrict__ out) {
    #pragma clang fp contract(off)
    int i = blockIdx.x * blockDim.x + threadIdx.x;
    if (i >= S_STAGES * K_CODES) return;
    const float* p = cb + (size_t)i * D_DIM;
    float tot = 0.0f;
    for (int h = 0; h < 256; h += 128) {
        const float* q = p + h;
        float r[8];
        #pragma unroll
        for (int j = 0; j < 8; ++j) { float v = q[j]; r[j] = v * v; }
        for (int t = 8; t < 128; t += 8) {
            #pragma unroll
            for (int j = 0; j < 8; ++j) { float v = q[t + j]; r[j] = r[j] + v * v; }
        }
        float res = ((r[0] + r[1]) + (r[2] + r[3])) + ((r[4] + r[5]) + (r[6] + r[7]));
        tot = tot + res;
    }
    out[i] = tot;
}

// ---------- precompute codebook 3-term bf16 splits, layout [S][8 dc][K][32] ----------
__global__ void k_splitB(const float* __restrict__ cb,
                         unsigned short* __restrict__ Bh,
                         unsigned short* __restrict__ Bm,
                         unsigned short* __restrict__ Bl) {
    const int TOT = S_STAGES * K_CODES * D_DIM;
    for (int e = blockIdx.x * blockDim.x + threadIdx.x; e < TOT; e += gridDim.x * blockDim.x) {
        int s = e >> 18, k = (e >> 8) & 1023, d = e & 255;
        float x = cb[e];
        unsigned short h, m, l;
        split3(x, h, m, l);
        size_t o = ((((size_t)s * 8 + (d >> 5)) * K_CODES) + k) * 32 + (d & 31);
        Bh[o] = h; Bm[o] = m; Bl[o] = l;
    }
}

// ---------- MFMA argmin: 128 tokens x 1024 codes per block ----------
__global__ __launch_bounds__(256, 2)
void k_argmin_mfma(const float* __restrict__ Rsrc,
                   const unsigned short* __restrict__ Bh,
                   const unsigned short* __restrict__ Bm,
                   const unsigned short* __restrict__ Bl,
                   const float* __restrict__ ss_s,
                   const int sidx,
                   int* __restrict__ idx_int,
                   float* __restrict__ idx_f)
{
    __shared__ __align__(16) unsigned short Ap0[128 * LDSW];
    __shared__ __align__(16) unsigned short Ap1[128 * LDSW];
    __shared__ __align__(16) unsigned short Ap2[128 * LDSW];
    __shared__ __align__(16) unsigned short Bp0[128 * LDSW];
    __shared__ __align__(16) unsigned short Bp1[128 * LDSW];
    __shared__ __align__(16) unsigned short Bp2[128 * LDSW];
    __shared__ float redD[128];
    __shared__ int   redI[128];

    const int tid = threadIdx.x;
    const int lane = tid & 63, w = tid >> 6;
    const int wr = w >> 1, wc = w & 1;
    const int r15 = lane & 15, g = lane >> 4;
    const int tokbase = blockIdx.x * 128;

    const int arow = tid & 127, ah = tid >> 7;   // A staging: 2 threads/row, 16 floats each
    const int brow = tid >> 1,  bhh = tid & 1;   // B staging: 2 threads/row, 16 bf16 each

    float best[4][4];
    int   besti[4][4];
    #pragma unroll
    for (int mt = 0; mt < 4; ++mt)
        #pragma unroll
        for (int j = 0; j < 4; ++j) { best[mt][j] = 3.4e38f; besti[mt][j] = 0; }

    for (int kt = 0; kt < 8; ++kt) {
        f32x4 acc[4][4];
        #pragma unroll
        for (int mt = 0; mt < 4; ++mt)
            #pragma unroll
            for (int nt = 0; nt < 4; ++nt) acc[mt][nt] = (f32x4){0.f, 0.f, 0.f, 0.f};

        for (int dc = 0; dc < 8; ++dc) {
            __syncthreads();
            // ---- stage A: read 16 fp32 of residual, 3-term split, write LDS ----
            {
                const float4* asrc = (const float4*)(Rsrc + (size_t)(tokbase + arow) * D_DIM + dc * 32 + ah * 16);
                float xs[16];
                float4 t0 = asrc[0], t1 = asrc[1], t2 = asrc[2], t3 = asrc[3];
                xs[0]=t0.x; xs[1]=t0.y; xs[2]=t0.z; xs[3]=t0.w;
                xs[4]=t1.x; xs[5]=t1.y; xs[6]=t1.z; xs[7]=t1.w;
                xs[8]=t2.x; xs[9]=t2.y; xs[10]=t2.z; xs[11]=t2.w;
                xs[12]=t3.x; xs[13]=t3.y; xs[14]=t3.z; xs[15]=t3.w;
                unsigned wh[8], wm[8], wl[8];
                #pragma unroll
                for (int j = 0; j < 8; ++j) {
                    unsigned short h0, m0, l0, h1, m1, l1;
                    split3(xs[2*j],   h0, m0, l0);
                    split3(xs[2*j+1], h1, m1, l1);
                    wh[j] = (unsigned)h0 | ((unsigned)h1 << 16);
                    wm[j] = (unsigned)m0 | ((unsigned)m1 << 16);
                    wl[j] = (unsigned)l0 | ((unsigned)l1 << 16);
                }
                const int o = arow * LDSW + ah * 16;
                uint4* d0 = (uint4*)&Ap0[o];
                d0[0] = (uint4){wh[0], wh[1], wh[2], wh[3]};
                d0[1] = (uint4){wh[4], wh[5], wh[6], wh[7]};
                uint4* d1 = (uint4*)&Ap1[o];
                d1[0] = (uint4){wm[0], wm[1], wm[2], wm[3]};
                d1[1] = (uint4){wm[4], wm[5], wm[6], wm[7]};
                uint4* d2 = (uint4*)&Ap2[o];
                d2[0] = (uint4){wl[0], wl[1], wl[2], wl[3]};
                d2[1] = (uint4){wl[4], wl[5], wl[6], wl[7]};
            }
            // ---- stage B: copy precomputed splits ----
            {
                const size_t gbase = ((((size_t)sidx * 8 + dc) * K_CODES) + kt * 128 + brow) * 32 + bhh * 16;
                const int o = brow * LDSW + bhh * 16;
                {
                    const uint4* s4 = (const uint4*)(Bh + gbase);
                    uint4* d4 = (uint4*)&Bp0[o]; d4[0] = s4[0]; d4[1] = s4[1];
                }
                {
                    const uint4* s4 = (const uint4*)(Bm + gbase);
                    uint4* d4 = (uint4*)&Bp1[o]; d4[0] = s4[0]; d4[1] = s4[1];
                }
                {
                    const uint4* s4 = (const uint4*)(Bl + gbase);
                    uint4* d4 = (uint4*)&Bp2[o]; d4[0] = s4[0]; d4[1] = s4[1];
                }
            }
            __syncthreads();

            // ---- fragments + 96 MFMA ----
            s16x8 a0[4], a1[4], a2[4], bb[4];
            #pragma unroll
            for (int mt = 0; mt < 4; ++mt) {
                const int o = (wr * 64 + mt * 16 + r15) * LDSW + g * 8;
                a0[mt] = *(const s16x8*)&Ap0[o];
                a1[mt] = *(const s16x8*)&Ap1[o];
                a2[mt] = *(const s16x8*)&Ap2[o];
            }
            // group B=hi: A in {h,m,l}
            #pragma unroll
            for (int nt = 0; nt < 4; ++nt)
                bb[nt] = *(const s16x8*)&Bp0[(wc * 64 + nt * 16 + r15) * LDSW + g * 8];
            #pragma unroll
            for (int mt = 0; mt < 4; ++mt)
                #pragma unroll
                for (int nt = 0; nt < 4; ++nt)
                    acc[mt][nt] = __builtin_amdgcn_mfma_f32_16x16x32_bf16(a0[mt], bb[nt], acc[mt][nt], 0, 0, 0);
            #pragma unroll
            for (int mt = 0; mt < 4; ++mt)
                #pragma unroll
                for (int nt = 0; nt < 4; ++nt)
                    acc[mt][nt] = __builtin_amdgcn_mfma_f32_16x16x32_bf16(a1[mt], bb[nt], acc[mt][nt], 0, 0, 0);
            #pragma unroll
            for (int mt = 0; mt < 4; ++mt)
                #pragma unroll
                for (int nt = 0; nt < 4; ++nt)
                    acc[mt][nt] = __builtin_amdgcn_mfma_f32_16x16x32_bf16(a2[mt], bb[nt], acc[mt][nt], 0, 0, 0);
            // group B=mid: A in {h,m}
            #pragma unroll
            for (int nt = 0; nt < 4; ++nt)
                bb[nt] = *(const s16x8*)&Bp1[(wc * 64 + nt * 16 + r15) * LDSW + g * 8];
            #pragma unroll
            for (int mt = 0; mt < 4; ++mt)
                #pragma unroll
                for (int nt = 0; nt < 4; ++nt)
                    acc[mt][nt] = __builtin_amdgcn_mfma_f32_16x16x32_bf16(a0[mt], bb[nt], acc[mt][nt], 0, 0, 0);
            #pragma unroll
            for (int mt = 0; mt < 4; ++mt)
                #pragma unroll
                for (int nt = 0; nt < 4; ++nt)
                    acc[mt][nt] = __builtin_amdgcn_mfma_f32_16x16x32_bf16(a1[mt], bb[nt], acc[mt][nt], 0, 0, 0);
            // group B=lo: A in {h}
            #pragma unroll
            for (int nt = 0; nt < 4; ++nt)
                bb[nt] = *(const s16x8*)&Bp2[(wc * 64 + nt * 16 + r15) * LDSW + g * 8];
            #pragma unroll
            for (int mt = 0; mt < 4; ++mt)
                #pragma unroll
                for (int nt = 0; nt < 4; ++nt)
                    acc[mt][nt] = __builtin_amdgcn_mfma_f32_16x16x32_bf16(a0[mt], bb[nt], acc[mt][nt], 0, 0, 0);
        }

        // ---- epilogue: dist = ss - 2*dot, running first-min (k ascending) ----
        #pragma unroll
        for (int nt = 0; nt < 4; ++nt) {
            const int kcol = kt * 128 + wc * 64 + nt * 16 + r15;
            const float ssv = ss_s[kcol];
            #pragma unroll
            for (int mt = 0; mt < 4; ++mt) {
                #pragma unroll
                for (int j = 0; j < 4; ++j) {
                    const float dist = ssv - 2.0f * acc[mt][nt][j];
                    if (dist < best[mt][j]) { best[mt][j] = dist; besti[mt][j] = kcol; }
                }
            }
        }
    }

    // ---- reduce over the 16 col-lanes within each warp ----
    float rbd[4][4];
    int   rbi[4][4];
    #pragma unroll
    for (int mt = 0; mt < 4; ++mt) {
        #pragma unroll
        for (int j = 0; j < 4; ++j) {
            float bd = best[mt][j];
            int bi = besti[mt][j];
            #pragma unroll
            for (int mm = 1; mm <= 8; mm <<= 1) {
                const float od = __shfl_xor(bd, mm, 64);
                const int oi = __shfl_xor(bi, mm, 64);
                if (od < bd || (od == bd && oi < bi)) { bd = od; bi = oi; }
            }
            rbd[mt][j] = bd; rbi[mt][j] = bi;
        }
    }
    // ---- cross-warp combine: wc==1 deposits, wc==0 merges + writes ----
    __syncthreads();
    #pragma unroll
    for (int mt = 0; mt < 4; ++mt)
        #pragma unroll
        for (int j = 0; j < 4; ++j)
            if (wc == 1 && r15 == 0) {
                const int trow = wr * 64 + mt * 16 + g * 4 + j;
                redD[trow] = rbd[mt][j];
                redI[trow] = rbi[mt][j];
            }
    __syncthreads();
    #pragma unroll
    for (int mt = 0; mt < 4; ++mt)
        #pragma unroll
        for (int j = 0; j < 4; ++j)
            if (wc == 0 && r15 == 0) {
                const int trow = wr * 64 + mt * 16 + g * 4 + j;
                float bd = rbd[mt][j];
                int bi = rbi[mt][j];
                const float od = redD[trow];
                const int oi = redI[trow];
                if (od < bd || (od == bd && oi < bi)) { bd = od; bi = oi; }
                const int n = tokbase + trow;
                idx_int[n] = bi;
                idx_f[n] = (float)bi;
            }
}

// ---------- counting sort: histogram ----------
__global__ void k_hist(const int* __restrict__ idx_s, int* __restrict__ hist, const int Nt) {
    __shared__ int lh[K_CODES];
    for (int i = threadIdx.x; i < K_CODES; i += blockDim.x) lh[i] = 0;
    __syncthreads();
    for (int n = blockIdx.x * blockDim.x + threadIdx.x; n < Nt; n += gridDim.x * blockDim.x)
        atomicAdd(&lh[idx_s[n]], 1);
    __syncthreads();
    for (int i = threadIdx.x; i < K_CODES; i += blockDim.x)
        if (lh[i]) atomicAdd(&hist[i], lh[i]);
}

// ---------- prefix sum over 1024 bins (1 block, 256 threads) ----------
__global__ void k_scan(const int* __restrict__ hist, int* __restrict__ off,
                       int* __restrict__ cursor) {
    __shared__ int tsum[256];
    const int t = threadIdx.x;
    int v[4], s = 0;
    #pragma unroll
    for (int j = 0; j < 4; ++j) { v[j] = hist[t * 4 + j]; s += v[j]; }
    tsum[t] = s;
    __syncthreads();
    if (t == 0) {
        int run = 0;
        for (int i = 0; i < 256; ++i) { int x = tsum[i]; tsum[i] = run; run += x; }
    }
    __syncthreads();
    int run = tsum[t];
    #pragma unroll
    for (int j = 0; j < 4; ++j) {
        off[t * 4 + j] = run;
        cursor[t * 4 + j] = run;
        run += v[j];
    }
    if (t == 255) off[K_CODES] = run;
}

// ---------- scatter tokens into per-code lists ----------
__global__ void k_scatter(const int* __restrict__ idx_s, int* __restrict__ cursor,
                          int* __restrict__ perm, const int Nt) {
    for (int n = blockIdx.x * blockDim.x + threadIdx.x; n < Nt; n += gridDim.x * blockDim.x) {
        const int pos = atomicAdd(&cursor[idx_s[n]], 1);
        perm[pos] = n;
    }
}

// ---------- balanced chunked segment sum over sorted tokens ----------
__global__ __launch_bounds__(256) void k_chunksum(const float* __restrict__ Rsrc,
                                                  const int* __restrict__ perm,
                                                  const int* __restrict__ idx_s,
                                                  float* __restrict__ accum) {
    __shared__ int pl[CHUNK];
    __shared__ int kl[CHUNK];
    const int t = threadIdx.x;
    const int base = blockIdx.x * CHUNK;
    if (t < CHUNK) pl[t] = perm[base + t];
    __syncthreads();
    if (t < CHUNK) kl[t] = idx_s[pl[t]];
    __syncthreads();
    float acc = 0.0f;
    int cur = kl[0];
    for (int m = 0; m < CHUNK; ++m) {
        const int k = kl[m];               // wave-uniform
        if (k != cur) {
            atomicAdd(&accum[(size_t)cur * D_DIM + t], acc);
            acc = 0.0f;
            cur = k;
        }
        acc += Rsrc[(size_t)pl[m] * D_DIM + t];
    }
    atomicAdd(&accum[(size_t)cur * D_DIM + t], acc);
}

// ---------- EMA finalize from complete sums + counts ----------
__global__ void k_ema_final(const float* __restrict__ accum,
                            const int* __restrict__ hist,
                            const float* __restrict__ N_in,     // + s*K
                            const float* __restrict__ zavg_in,  // + s*K*D
                            float* __restrict__ out_N,
                            float* __restrict__ out_zavg,
                            float* __restrict__ out_cb) {
    const int k = blockIdx.x, t = threadIdx.x;
    const float cnt = (float)hist[k];
    const float zk = accum[(size_t)k * D_DIM + t] / (cnt + EPS_F);
    const float Ns = DECAY * N_in[k] + (1.0f - DECAY) * cnt;
    const float za = DECAY * zavg_in[(size_t)k * D_DIM + t] + (1.0f - DECAY) * zk;
    out_zavg[(size_t)k * D_DIM + t] = za;
    out_cb[(size_t)k * D_DIM + t] = za / (Ns + EPS_F);
    if (t == 0) out_N[k] = Ns;
}

// ---------- residual update + per-stage loss (mode 1: final stage writes z_q) ----------
__global__ void k_resid(const float* __restrict__ Rsrc, const float* __restrict__ z,
                        const float* __restrict__ cb_s, const int* __restrict__ idx_s,
                        float* __restrict__ Rdst, float* __restrict__ out_zq,
                        float* __restrict__ loss_s, const int mode, const int total4) {
    float lp = 0.0f;
    for (int i = blockIdx.x * blockDim.x + threadIdx.x; i < total4; i += gridDim.x * blockDim.x) {
        const int n = i >> 6;
        const int c = (i & 63) << 2;
        const int k = idx_s[n];
        const float4 r = *(const float4*)(Rsrc + (size_t)n * D_DIM + c);
        const float4 q = *(const float4*)(cb_s + (size_t)k * D_DIM + c);
        const float dx = q.x - r.x, dy = q.y - r.y, dz = q.z - r.z, dw = q.w - r.w;
        lp += dx * dx + dy * dy + dz * dz + dw * dw;
        if (mode == 0) {
            float4 o;
            o.x = r.x - q.x; o.y = r.y - q.y; o.z = r.z - q.z; o.w = r.w - q.w;
            *(float4*)(Rdst + (size_t)n * D_DIM + c) = o;
        } else {
            const float4 zv = *(const float4*)(z + (size_t)n * D_DIM + c);
            float4 o;
            o.x = (zv.x - r.x) + q.x;
            o.y = (zv.y - r.y) + q.y;
            o.z = (zv.z - r.z) + q.z;
            o.w = (zv.w - r.w) + q.w;
            *(float4*)(out_zq + (size_t)n * D_DIM + c) = o;
        }
    }
    #pragma unroll
    for (int offs = 32; offs > 0; offs >>= 1) lp += __shfl_down(lp, offs, 64);
    __shared__ float wsum[4];
    const int lane = threadIdx.x & 63, w = threadIdx.x >> 6;
    if (lane == 0) wsum[w] = lp;
    __syncthreads();
    if (threadIdx.x == 0) atomicAdd(loss_s, (wsum[0] + wsum[1]) + (wsum[2] + wsum[3]));
}

__global__ void k_loss_final(const float* __restrict__ loss_acc,
                             float* __restrict__ out_loss, const float meanDiv) {
    if (threadIdx.x == 0 && blockIdx.x == 0) {
        float loss = 0.0f;
        #pragma unroll
        for (int s = 0; s < S_STAGES; ++s) loss = loss + BETA * (loss_acc[s] / meanDiv);
        out_loss[0] = loss;
    }
}

extern "C" void kernel_launch(void* const* d_in, const int* in_sizes, int n_in,
                              void* d_out, int out_size, void* d_ws, size_t ws_size,
                              hipStream_t stream)
{
    const float* z = (const float*)d_in[0];
    const float* cb = (const float*)d_in[1];
    const float* N_in = (const float*)d_in[2];
    const float* zavg = (const float*)d_in[3];
    float* out = (float*)d_out;

    const int Nt = in_sizes[0] / D_DIM;      // 65536
    const int total4 = Nt * (D_DIM / 4);

    // ---- workspace layout (~75.7 MB) ----
    char* wp = (char*)d_ws;
    int* idx_ws = (int*)wp;                 wp += (size_t)S_STAGES * Nt * 4;
    int* perm   = (int*)wp;                 wp += (size_t)Nt * 4;
    int* hist   = (int*)wp;                 wp += K_CODES * 4;
    int* cursor = (int*)wp;                 wp += K_CODES * 4;
    int* off    = (int*)wp;                 wp += (K_CODES + 8) * 4;
    float* sumsq = (float*)wp;              wp += S_STAGES * K_CODES * 4;
    float* lossa = (float*)wp;              wp += 64;
    float* accum = (float*)wp;              wp += (size_t)K_CODES * D_DIM * 4;
    unsigned short* Bh = (unsigned short*)wp; wp += (size_t)S_STAGES * K_CODES * D_DIM * 2;
    unsigned short* Bm = (unsigned short*)wp; wp += (size_t)S_STAGES * K_CODES * D_DIM * 2;
    unsigned short* Bl = (unsigned short*)wp; wp += (size_t)S_STAGES * K_CODES * D_DIM * 2;
    wp = (char*)(((size_t)wp + 255) & ~(size_t)255);
    float* Rbuf = (float*)wp;               // Nt * D fp32 (64 MB)

    const size_t ZQ_OFF = 0;
    const size_t LOSS_OFF = (size_t)Nt * D_DIM;
    const size_t IDX_OFF = LOSS_OFF + 1;
    const size_t CB_OFF = IDX_OFF + (size_t)S_STAGES * Nt;
    const size_t N_OFF = CB_OFF + (size_t)S_STAGES * K_CODES * D_DIM;
    const size_t ZAVG_OFF = N_OFF + (size_t)S_STAGES * K_CODES;

    hipMemsetAsync(lossa, 0, 64, stream);
    k_sumsq<<<(S_STAGES * K_CODES + 255) / 256, 256, 0, stream>>>(cb, sumsq);
    k_splitB<<<1024, 256, 0, stream>>>(cb, Bh, Bm, Bl);

    for (int s = 0; s < S_STAGES; ++s) {
        const float* Rsrc = (s == 0) ? z : Rbuf;
        int* idx_s = idx_ws + (size_t)s * Nt;
        k_argmin_mfma<<<Nt / 128, 256, 0, stream>>>(
            Rsrc, Bh, Bm, Bl, sumsq + s * K_CODES, s,
            idx_s, out + IDX_OFF + (size_t)s * Nt);
        hipMemsetAsync(hist, 0, K_CODES * 4, stream);
        hipMemsetAsync(accum, 0, (size_t)K_CODES * D_DIM * 4, stream);
        k_hist<<<64, 256, 0, stream>>>(idx_s, hist, Nt);
        k_scan<<<1, 256, 0, stream>>>(hist, off, cursor);
        k_scatter<<<64, 256, 0, stream>>>(idx_s, cursor, perm, Nt);
        k_chunksum<<<Nt / CHUNK, 256, 0, stream>>>(Rsrc, perm, idx_s, accum);
        k_ema_final<<<K_CODES, 256, 0, stream>>>(
            accum, hist,
            N_in + s * K_CODES, zavg + (size_t)s * K_CODES * D_DIM,
            out + N_OFF + s * K_CODES,
            out + ZAVG_OFF + (size_t)s * K_CODES * D_DIM,
            out + CB_OFF + (size_t)s * K_CODES * D_DIM);
        k_resid<<<2048, 256, 0, stream>>>(
            Rsrc, z, cb + (size_t)s * K_CODES * D_DIM, idx_s,
            Rbuf, out + ZQ_OFF, lossa + s, (s == 3) ? 1 : 0, total4);
    }
    k_loss_final<<<1, 64, 0, stream>>>(lossa, out + LOSS_OFF, (float)((size_t)Nt * D_DIM));
}